// Round 3
// baseline (567.230 us; speedup 1.0000x reference)
//
#include <hip/hip_runtime.h>
#include <hip/hip_bf16.h>

typedef __bf16 bf16;
typedef __bf16 bf16x8 __attribute__((ext_vector_type(8)));
typedef __bf16 bf16x4 __attribute__((ext_vector_type(4)));
typedef float f32x4 __attribute__((ext_vector_type(4)));

#define LOG2E 1.44269504088896340736f

// ---------------- K1: transpose x[b][i][n] (f32) -> xt[b][n][i] (bf16), 64x64 tiles ----
__global__ __launch_bounds__(256) void k_transpose(const float* __restrict__ src,
                                                   bf16* __restrict__ dst) {
  __shared__ bf16 T[64][72];
  const int t = threadIdx.x;
  const int n0 = blockIdx.x * 64;
  const int i0 = blockIdx.y * 64;
  const int b = blockIdx.z;
  const size_t srcb = (size_t)b * 1024 * 2048;
#pragma unroll
  for (int p = 0; p < 2; ++p) {
    int idx = p * 256 + t;
    int row = idx >> 3;   // i-local
    int seg = idx & 7;    // 8 n elems
    const float* sp = src + srcb + (size_t)(i0 + row) * 2048 + n0 + seg * 8;
    f32x4 a = *(const f32x4*)sp;
    f32x4 c = *(const f32x4*)(sp + 4);
    bf16x8 o;
#pragma unroll
    for (int e = 0; e < 4; ++e) { o[e] = (bf16)a[e]; o[4 + e] = (bf16)c[e]; }
    *(bf16x8*)&T[row][seg * 8] = o;
  }
  __syncthreads();
  const int j = t >> 2;       // n-local
  const int iseg = t & 3;     // 16 i elems
  bf16x8 o0, o1;
#pragma unroll
  for (int e = 0; e < 8; ++e) o0[e] = T[iseg * 16 + e][j];
#pragma unroll
  for (int e = 0; e < 8; ++e) o1[e] = T[iseg * 16 + 8 + e][j];
  bf16* dp = dst + (size_t)b * 2048 * 1024 + (size_t)(n0 + j) * 1024 + i0 + iseg * 16;
  *(bf16x8*)dp = o0;
  *(bf16x8*)(dp + 8) = o1;
}

// ---------------- K2: GEMM  C[b][o][n] = W(o,k) * Bt[b][n][k] + bias[o] ----------------
// W row-major k-contig (bf16); Bt (n,k) k-contig (bf16). M=K=1024, Nn=2048.
template <typename OT>
__global__ __launch_bounds__(256) void k_gemm(const bf16* __restrict__ A,
                                              const bf16* __restrict__ Bt,
                                              const float* __restrict__ bias,
                                              OT* __restrict__ C,
                                              int M, int K, int Nn) {
  __shared__ bf16 As[128][40];
  __shared__ bf16 Bs[128][40];
  const int t = threadIdx.x;
  const int w = t >> 6, l = t & 63, q = l >> 4, li = l & 15;
  const int o0 = blockIdx.y * 128, n0 = blockIdx.x * 128;
  const int b = blockIdx.z;
  const bf16* Bb = Bt + (size_t)b * Nn * K;
  const int wr = (w >> 1) * 64, wc = (w & 1) * 64;
  f32x4 acc[4][4];
#pragma unroll
  for (int i = 0; i < 4; ++i)
#pragma unroll
    for (int j = 0; j < 4; ++j) acc[i][j] = (f32x4){0.f, 0.f, 0.f, 0.f};

  for (int k0 = 0; k0 < K; k0 += 32) {
    __syncthreads();
#pragma unroll
    for (int p = 0; p < 2; ++p) {
      int idx = p * 256 + t;
      int row = idx >> 2, seg = idx & 3;
      *(bf16x8*)&As[row][seg * 8] =
          *(const bf16x8*)(A + (size_t)(o0 + row) * K + k0 + seg * 8);
      *(bf16x8*)&Bs[row][seg * 8] =
          *(const bf16x8*)(Bb + (size_t)(n0 + row) * K + k0 + seg * 8);
    }
    __syncthreads();
    bf16x8 af[4], bfr[4];
#pragma unroll
    for (int mt = 0; mt < 4; ++mt) af[mt] = *(const bf16x8*)&As[wr + mt * 16 + li][q * 8];
#pragma unroll
    for (int c = 0; c < 4; ++c) bfr[c] = *(const bf16x8*)&Bs[wc + c * 16 + li][q * 8];
#pragma unroll
    for (int mt = 0; mt < 4; ++mt)
#pragma unroll
      for (int c = 0; c < 4; ++c)
        acc[mt][c] = __builtin_amdgcn_mfma_f32_16x16x32_bf16(af[mt], bfr[c], acc[mt][c], 0, 0, 0);
  }

  OT* Cb = C + (size_t)b * M * Nn;
#pragma unroll
  for (int mt = 0; mt < 4; ++mt) {
#pragma unroll
    for (int r = 0; r < 4; ++r) {
      int o = o0 + wr + mt * 16 + q * 4 + r;
      float bv = bias[o];
#pragma unroll
      for (int c = 0; c < 4; ++c) {
        int n = n0 + wc + c * 16 + li;
        Cb[(size_t)o * Nn + n] = (OT)(acc[mt][c][r] + bv);
      }
    }
  }
}

// ---------------- K3: RoPE + per-head transpose: p[b][hd*16+h][n] -> a[b][h][n][hd] ----
__global__ __launch_bounds__(256) void k_rope(const bf16* __restrict__ src,
                                              const float* __restrict__ enc,
                                              bf16* __restrict__ dst) {
  __shared__ bf16 T[64][72];
  const int t = threadIdx.x;
  const int n0 = blockIdx.x * 64;
  const int h = blockIdx.y;
  const int b = blockIdx.z;
#pragma unroll
  for (int p = 0; p < 2; ++p) {
    int idx = p * 256 + t;
    int hd = idx >> 3;   // hd-local (row d = hd*16+h)
    int seg = idx & 7;
    *(bf16x8*)&T[hd][seg * 8] =
        *(const bf16x8*)(src + (size_t)(b * 1024 + hd * 16 + h) * 2048 + n0 + seg * 8);
  }
  __syncthreads();
  const int j = t >> 2;          // n-local
  const int hd0 = (t & 3) * 16;  // 16 hd elems
  const int n = n0 + j;
  const float* e0 = enc + (size_t)n * 64 + hd0;
  const float* e1 = enc + (size_t)2048 * 64 + (size_t)n * 64 + hd0;
  bf16x8 o0, o1;
#pragma unroll
  for (int i = 0; i < 8; ++i) {
    int e = 2 * i;          // pair within 16-block (hd0 even)
    float t0 = (float)T[hd0 + e][j];
    float t1 = (float)T[hd0 + e + 1][j];
    float f00 = e0[e], f01 = e0[e + 1];
    float f10 = e1[e], f11 = e1[e + 1];
    float r0 = t0 * f00 - t1 * f10;
    float r1 = t1 * f01 + t0 * f11;
    if (i < 4) { o0[e & 7] = (bf16)r0; o0[(e & 7) + 1] = (bf16)r1; }
    else       { o1[e & 7] = (bf16)r0; o1[(e & 7) + 1] = (bf16)r1; }
  }
  bf16* dp = dst + ((size_t)(b * 16 + h) * 2048 + n) * 64 + hd0;
  *(bf16x8*)dp = o0;
  *(bf16x8*)(dp + 8) = o1;
}

// ---------------- K4: flash attention ----------------
// qa/ka: [b][h][n][hd] (hd contig). vp: [b][hd*16+h][n] (n contig). out x: [b][n][h*64+hd]
__global__ __launch_bounds__(256) void k_attn(const bf16* __restrict__ qa,
                                              const bf16* __restrict__ ka,
                                              const bf16* __restrict__ vp,
                                              bf16* __restrict__ xo) {
  __shared__ bf16 Qs[64][72];
  __shared__ bf16 Ks[64][72];
  __shared__ bf16 Vs[64][72];   // [hd][m]
  __shared__ bf16 Ps[4][16][72];
  const int t = threadIdx.x;
  const int w = t >> 6, l = t & 63, q = l >> 4, li = l & 15;
  const int n0 = blockIdx.x * 64, h = blockIdx.y, b = blockIdx.z;
  const bf16* Qb = qa + (size_t)(b * 16 + h) * 2048 * 64;
  const bf16* Kb = ka + (size_t)(b * 16 + h) * 2048 * 64;
  const bf16* Vb = vp + (size_t)b * 1024 * 2048 + (size_t)h * 2048;  // + hd*16*2048

#pragma unroll
  for (int p = 0; p < 2; ++p) {
    int idx = p * 256 + t;
    int row = idx >> 3, seg = idx & 7;
    *(bf16x8*)&Qs[row][seg * 8] = *(const bf16x8*)(Qb + (size_t)(n0 + row) * 64 + seg * 8);
  }

  f32x4 acc_o[4];
#pragma unroll
  for (int c = 0; c < 4; ++c) acc_o[c] = (f32x4){0.f, 0.f, 0.f, 0.f};
  float m_i[4], l_i[4];
#pragma unroll
  for (int r = 0; r < 4; ++r) { m_i[r] = -1e30f; l_i[r] = 0.f; }

  for (int m0 = 0; m0 < 2048; m0 += 64) {
    __syncthreads();
#pragma unroll
    for (int p = 0; p < 2; ++p) {
      int idx = p * 256 + t;
      int row = idx >> 3, seg = idx & 7;
      *(bf16x8*)&Ks[row][seg * 8] = *(const bf16x8*)(Kb + (size_t)(m0 + row) * 64 + seg * 8);
      *(bf16x8*)&Vs[row][seg * 8] = *(const bf16x8*)(Vb + (size_t)row * (16 * 2048) + m0 + seg * 8);
    }
    __syncthreads();

    // S = Q K^T  (wave's 16 rows x 64 cols)
    f32x4 sacc[4];
#pragma unroll
    for (int c = 0; c < 4; ++c) sacc[c] = (f32x4){0.f, 0.f, 0.f, 0.f};
#pragma unroll
    for (int kk = 0; kk < 2; ++kk) {
      bf16x8 a = *(const bf16x8*)&Qs[w * 16 + li][kk * 32 + q * 8];
#pragma unroll
      for (int c = 0; c < 4; ++c) {
        bf16x8 bb = *(const bf16x8*)&Ks[c * 16 + li][kk * 32 + q * 8];
        sacc[c] = __builtin_amdgcn_mfma_f32_16x16x32_bf16(a, bb, sacc[c], 0, 0, 0);
      }
    }

    // online softmax (rows = q*4+r within wave's 16)
    float mt_[4];
#pragma unroll
    for (int r = 0; r < 4; ++r) {
      float mx = -1e30f;
#pragma unroll
      for (int c = 0; c < 4; ++c) { sacc[c][r] *= 0.125f; mx = fmaxf(mx, sacc[c][r]); }
      mt_[r] = mx;
    }
#pragma unroll
    for (int r = 0; r < 4; ++r) {
#pragma unroll
      for (int off = 1; off < 16; off <<= 1)
        mt_[r] = fmaxf(mt_[r], __shfl_xor(mt_[r], off));
    }
    float p_[4][4];
#pragma unroll
    for (int r = 0; r < 4; ++r) {
      float mnew = fmaxf(m_i[r], mt_[r]);
      float alpha = exp2f((m_i[r] - mnew) * LOG2E);
      m_i[r] = mnew;
      float s = 0.f;
#pragma unroll
      for (int c = 0; c < 4; ++c) {
        float pv = exp2f((sacc[c][r] - mnew) * LOG2E);
        p_[c][r] = pv;
        s += pv;
      }
#pragma unroll
      for (int off = 1; off < 16; off <<= 1) s += __shfl_xor(s, off);
      l_i[r] = l_i[r] * alpha + s;
#pragma unroll
      for (int c = 0; c < 4; ++c) acc_o[c][r] *= alpha;
    }
    // P -> LDS (A-operand layout round-trip)
#pragma unroll
    for (int c = 0; c < 4; ++c)
#pragma unroll
      for (int r = 0; r < 4; ++r)
        Ps[w][q * 4 + r][c * 16 + li] = (bf16)p_[c][r];

    // O += P V
#pragma unroll
    for (int kk = 0; kk < 2; ++kk) {
      bf16x8 a = *(const bf16x8*)&Ps[w][li][kk * 32 + q * 8];
#pragma unroll
      for (int c = 0; c < 4; ++c) {
        bf16x8 bb = *(const bf16x8*)&Vs[c * 16 + li][kk * 32 + q * 8];
        acc_o[c] = __builtin_amdgcn_mfma_f32_16x16x32_bf16(a, bb, acc_o[c], 0, 0, 0);
      }
    }
  }

  float inv[4];
#pragma unroll
  for (int r = 0; r < 4; ++r) inv[r] = 1.0f / l_i[r];
  bf16* xb = xo + (size_t)b * 2048 * 1024 + (size_t)h * 64;
#pragma unroll
  for (int r = 0; r < 4; ++r) {
    int n = n0 + w * 16 + q * 4 + r;
#pragma unroll
    for (int c = 0; c < 4; ++c)
      xb[(size_t)n * 1024 + c * 16 + li] = (bf16)(acc_o[c][r] * inv[r]);
  }
}

// ---------------- K5: convert Wq/Wk/Wv f32 -> bf16 ----------------
__global__ __launch_bounds__(256) void k_cvtw(const float* __restrict__ Wq,
                                              const float* __restrict__ Wk,
                                              const float* __restrict__ Wv,
                                              bf16* __restrict__ oq,
                                              bf16* __restrict__ ok,
                                              bf16* __restrict__ ov) {
  const int which = blockIdx.y;
  const float* s = (which == 0) ? Wq : ((which == 1) ? Wk : Wv);
  bf16* d = (which == 0) ? oq : ((which == 1) ? ok : ov);
  int idx = (blockIdx.x * 256 + threadIdx.x) * 4;
  f32x4 a = *(const f32x4*)(s + idx);
  bf16x4 o;
#pragma unroll
  for (int e = 0; e < 4; ++e) o[e] = (bf16)a[e];
  *(bf16x4*)(d + idx) = o;
}

// ---------------- K6: permute Wm columns: Wmp[o][h*64+hd] = Wm[o][hd*16+h], f32->bf16 --
__global__ __launch_bounds__(256) void k_permw(const float* __restrict__ Wm,
                                               bf16* __restrict__ Wmp) {
  int idx = blockIdx.x * 256 + threadIdx.x;
  int o = idx >> 10, j = idx & 1023;
  int hd = j & 63, hh = j >> 6;
  Wmp[idx] = (bf16)Wm[((size_t)o << 10) + (size_t)(hd * 16 + hh)];
}

extern "C" void kernel_launch(void* const* d_in, const int* in_sizes, int n_in,
                              void* d_out, int out_size, void* d_ws, size_t ws_size,
                              hipStream_t stream) {
  const float* query = (const float*)d_in[0];
  const float* key   = (const float*)d_in[1];
  const float* value = (const float*)d_in[2];
  const float* enc   = (const float*)d_in[3];
  const float* Wq = (const float*)d_in[4];  const float* bq = (const float*)d_in[5];
  const float* Wk = (const float*)d_in[6];  const float* bk = (const float*)d_in[7];
  const float* Wv = (const float*)d_in[8];  const float* bv = (const float*)d_in[9];
  const float* Wm = (const float*)d_in[10]; const float* bm = (const float*)d_in[11];

  // Workspace: 4 ping-pong 16 MB buffers + 4 bf16 weights = 72 MB peak.
  char* ws = (char*)d_ws;
  const size_t SZ = (size_t)4 * 2048 * 1024 * 2;  // 16 MB per [b][*][*] bf16 tensor
  const size_t WZ = (size_t)1024 * 1024 * 2;      // 2 MB per bf16 weight
  bf16* bufA = (bf16*)(ws + 0 * SZ);
  bf16* bufB = (bf16*)(ws + 1 * SZ);
  bf16* bufC = (bf16*)(ws + 2 * SZ);
  bf16* bufD = (bf16*)(ws + 3 * SZ);
  bf16* Wqb  = (bf16*)(ws + 4 * SZ + 0 * WZ);
  bf16* Wkb  = (bf16*)(ws + 4 * SZ + 1 * WZ);
  bf16* Wvb  = (bf16*)(ws + 4 * SZ + 2 * WZ);
  bf16* Wmp  = (bf16*)(ws + 4 * SZ + 3 * WZ);

  dim3 blk(256);
  k_cvtw<<<dim3(1024, 3), blk, 0, stream>>>(Wq, Wk, Wv, Wqb, Wkb, Wvb);
  k_permw<<<dim3(4096), blk, 0, stream>>>(Wm, Wmp);
  // A = q^T ; B = qp
  k_transpose<<<dim3(32, 16, 4), blk, 0, stream>>>(query, bufA);
  k_gemm<bf16><<<dim3(16, 8, 4), blk, 0, stream>>>(Wqb, bufA, bq, bufB, 1024, 1024, 2048);
  // A = k^T ; C = kp
  k_transpose<<<dim3(32, 16, 4), blk, 0, stream>>>(key, bufA);
  k_gemm<bf16><<<dim3(16, 8, 4), blk, 0, stream>>>(Wkb, bufA, bk, bufC, 1024, 1024, 2048);
  // A = v^T ; D = vp
  k_transpose<<<dim3(32, 16, 4), blk, 0, stream>>>(value, bufA);
  k_gemm<bf16><<<dim3(16, 8, 4), blk, 0, stream>>>(Wvb, bufA, bv, bufD, 1024, 1024, 2048);
  // rope: B(qp) -> A(qa); C(kp) -> B(ka)
  k_rope<<<dim3(32, 16, 4), blk, 0, stream>>>(bufB, enc, bufA);
  k_rope<<<dim3(32, 16, 4), blk, 0, stream>>>(bufC, enc, bufB);
  // attn: (A,B,D) -> C
  k_attn<<<dim3(32, 16, 4), blk, 0, stream>>>(bufA, bufB, bufD, bufC);
  // out GEMM: C -> d_out (f32)
  k_gemm<float><<<dim3(16, 8, 4), blk, 0, stream>>>(Wmp, bufC, bm, (float*)d_out, 1024, 1024, 2048);
}

// Round 5
// 480.634 us; speedup vs baseline: 1.1802x; 1.1802x over previous
//
#include <hip/hip_runtime.h>
#include <hip/hip_bf16.h>

typedef __bf16 bf16;
typedef __bf16 bf16x8 __attribute__((ext_vector_type(8)));
typedef __bf16 bf16x4 __attribute__((ext_vector_type(4)));
typedef float f32x4 __attribute__((ext_vector_type(4)));

#define LOG2E 1.44269504088896340736f

typedef __attribute__((address_space(1))) const unsigned int guint;
typedef __attribute__((address_space(3))) unsigned int luint;

__device__ __forceinline__ void gload_lds16(const bf16* g, bf16* l) {
  // async global->LDS, 16B per lane; LDS dest = wave-uniform base + lane*16
  __builtin_amdgcn_global_load_lds((guint*)g, (luint*)l, 16, 0, 0);
}

// ---------------- K1: transpose x[b][i][n] (f32) -> xt[b][n][i] (bf16), 64x64 tiles ----
__global__ __launch_bounds__(256) void k_transpose(const float* __restrict__ src,
                                                   bf16* __restrict__ dst) {
  __shared__ bf16 T[64][72];
  const int t = threadIdx.x;
  const int n0 = blockIdx.x * 64;
  const int i0 = blockIdx.y * 64;
  const int b = blockIdx.z;
  const size_t srcb = (size_t)b * 1024 * 2048;
#pragma unroll
  for (int p = 0; p < 2; ++p) {
    int idx = p * 256 + t;
    int row = idx >> 3;   // i-local
    int seg = idx & 7;    // 8 n elems
    const float* sp = src + srcb + (size_t)(i0 + row) * 2048 + n0 + seg * 8;
    f32x4 a = *(const f32x4*)sp;
    f32x4 c = *(const f32x4*)(sp + 4);
    bf16x8 o;
#pragma unroll
    for (int e = 0; e < 4; ++e) { o[e] = (bf16)a[e]; o[4 + e] = (bf16)c[e]; }
    *(bf16x8*)&T[row][seg * 8] = o;
  }
  __syncthreads();
  const int j = t >> 2;       // n-local
  const int iseg = t & 3;     // 16 i elems
  bf16x8 o0, o1;
#pragma unroll
  for (int e = 0; e < 8; ++e) o0[e] = T[iseg * 16 + e][j];
#pragma unroll
  for (int e = 0; e < 8; ++e) o1[e] = T[iseg * 16 + 8 + e][j];
  bf16* dp = dst + (size_t)b * 2048 * 1024 + (size_t)(n0 + j) * 1024 + i0 + iseg * 16;
  *(bf16x8*)dp = o0;
  *(bf16x8*)(dp + 8) = o1;
}

// ---------------- K2: GEMM  C[b][o][n] = W(o,k) * Bt[b][n][k] + bias[o] ----------------
// m97-style: global_load_lds width-16 staging into unpadded row-major [128][32] tiles.
template <typename OT>
__global__ __launch_bounds__(256) void k_gemm(const bf16* __restrict__ A,
                                              const bf16* __restrict__ Bt,
                                              const float* __restrict__ bias,
                                              OT* __restrict__ C,
                                              int M, int K, int Nn) {
  __shared__ bf16 As[128 * 32];
  __shared__ bf16 Bs[128 * 32];
  const int t = threadIdx.x;
  const int w = t >> 6, l = t & 63, q = l >> 4, li = l & 15;
  const int o0 = blockIdx.y * 128, n0 = blockIdx.x * 128;
  const int b = blockIdx.z;
  const bf16* Ab = A + (size_t)o0 * K;
  const bf16* Bb = Bt + (size_t)b * Nn * K + (size_t)n0 * K;
  const int wr = (w >> 1) * 64, wc = (w & 1) * 64;
  f32x4 acc[4][4];
#pragma unroll
  for (int i = 0; i < 4; ++i)
#pragma unroll
    for (int j = 0; j < 4; ++j) acc[i][j] = (f32x4){0.f, 0.f, 0.f, 0.f};

  // staging geometry: idx in [0,512): row = idx>>2 (128 rows), seg = idx&3 (4 x 8 elems)
  const int sidx0 = w * 64 + l;
  const int srow0 = sidx0 >> 2, sseg0 = (sidx0 & 3) * 8;
  const int sidx1 = 256 + sidx0;
  const int srow1 = sidx1 >> 2, sseg1 = (sidx1 & 3) * 8;
  bf16* ldsA0 = As + (size_t)(w * 64) * 8;        // wave-uniform bases
  bf16* ldsA1 = As + (size_t)(256 + w * 64) * 8;
  bf16* ldsB0 = Bs + (size_t)(w * 64) * 8;
  bf16* ldsB1 = Bs + (size_t)(256 + w * 64) * 8;

  for (int k0 = 0; k0 < K; k0 += 32) {
    __syncthreads();
    gload_lds16(Ab + (size_t)srow0 * K + k0 + sseg0, ldsA0);
    gload_lds16(Ab + (size_t)srow1 * K + k0 + sseg1, ldsA1);
    gload_lds16(Bb + (size_t)srow0 * K + k0 + sseg0, ldsB0);
    gload_lds16(Bb + (size_t)srow1 * K + k0 + sseg1, ldsB1);
    __syncthreads();
    bf16x8 af[4], bfr[4];
#pragma unroll
    for (int mt = 0; mt < 4; ++mt) af[mt] = *(const bf16x8*)&As[(wr + mt * 16 + li) * 32 + q * 8];
#pragma unroll
    for (int c = 0; c < 4; ++c) bfr[c] = *(const bf16x8*)&Bs[(wc + c * 16 + li) * 32 + q * 8];
#pragma unroll
    for (int mt = 0; mt < 4; ++mt)
#pragma unroll
      for (int c = 0; c < 4; ++c)
        acc[mt][c] = __builtin_amdgcn_mfma_f32_16x16x32_bf16(af[mt], bfr[c], acc[mt][c], 0, 0, 0);
  }

  OT* Cb = C + (size_t)b * M * Nn;
#pragma unroll
  for (int mt = 0; mt < 4; ++mt) {
#pragma unroll
    for (int r = 0; r < 4; ++r) {
      int o = o0 + wr + mt * 16 + q * 4 + r;
      float bv = bias[o];
#pragma unroll
      for (int c = 0; c < 4; ++c) {
        int n = n0 + wc + c * 16 + li;
        Cb[(size_t)o * Nn + n] = (OT)(acc[mt][c][r] + bv);
      }
    }
  }
}

// ---------------- K3: RoPE + per-head transpose: p[b][hd*16+h][n] -> a[b][h][n][hd] ----
// oscale folds the attention scale (and log2e) into Q so the attn kernel's softmax is
// a bare v_exp_f32.
__global__ __launch_bounds__(256) void k_rope(const bf16* __restrict__ src,
                                              const float* __restrict__ enc,
                                              bf16* __restrict__ dst,
                                              float oscale) {
  __shared__ bf16 T[64][72];
  const int t = threadIdx.x;
  const int n0 = blockIdx.x * 64;
  const int h = blockIdx.y;
  const int b = blockIdx.z;
#pragma unroll
  for (int p = 0; p < 2; ++p) {
    int idx = p * 256 + t;
    int hd = idx >> 3;   // hd-local (row d = hd*16+h)
    int seg = idx & 7;
    *(bf16x8*)&T[hd][seg * 8] =
        *(const bf16x8*)(src + (size_t)(b * 1024 + hd * 16 + h) * 2048 + n0 + seg * 8);
  }
  __syncthreads();
  const int j = t >> 2;          // n-local
  const int hd0 = (t & 3) * 16;  // 16 hd elems
  const int n = n0 + j;
  const float* e0 = enc + (size_t)n * 64 + hd0;
  const float* e1 = enc + (size_t)2048 * 64 + (size_t)n * 64 + hd0;
  bf16x8 o0, o1;
#pragma unroll
  for (int i = 0; i < 8; ++i) {
    int e = 2 * i;
    float t0 = (float)T[hd0 + e][j];
    float t1 = (float)T[hd0 + e + 1][j];
    float f00 = e0[e], f01 = e0[e + 1];
    float f10 = e1[e], f11 = e1[e + 1];
    float r0 = (t0 * f00 - t1 * f10) * oscale;
    float r1 = (t1 * f01 + t0 * f11) * oscale;
    if (i < 4) { o0[e & 7] = (bf16)r0; o0[(e & 7) + 1] = (bf16)r1; }
    else       { o1[e & 7] = (bf16)r0; o1[(e & 7) + 1] = (bf16)r1; }
  }
  bf16* dp = dst + ((size_t)(b * 16 + h) * 2048 + n) * 64 + hd0;
  *(bf16x8*)dp = o0;
  *(bf16x8*)(dp + 8) = o1;
}

// ---------------- K4: flash attention, S^T formulation, fixed-max softmax -------------
// qa/ka: [b][h][n][hd] (hd contig; qa pre-scaled by 0.125*log2e). vp: [b][hd*16+h][n].
// out x: [b][n][h*64+hd].
// Block: 256 thr = 4 waves; wave owns 32 q-cols; block tile = 128 q; K-tile = 128/iter.
__global__ __launch_bounds__(256) void k_attn(const bf16* __restrict__ qa,
                                              const bf16* __restrict__ ka,
                                              const bf16* __restrict__ vp,
                                              bf16* __restrict__ xo) {
  __shared__ bf16 Ks[128 * 72];    // [m][hd]
  __shared__ bf16 Vs[64 * 136];    // [hd][m]
  __shared__ bf16 Ps[4][32 * 136]; // per-wave P^T as [qcol][m]
  const int t = threadIdx.x;
  const int w = t >> 6, l = t & 63, q = l >> 4, li = l & 15;
  const int n0 = blockIdx.x * 128, h = blockIdx.y, b = blockIdx.z;
  const bf16* Qb = qa + (size_t)(b * 16 + h) * 2048 * 64;
  const bf16* Kb = ka + (size_t)(b * 16 + h) * 2048 * 64;
  const bf16* Vb = vp + (size_t)b * 1024 * 2048 + (size_t)h * 2048;  // + hd*16*2048
  bf16* Pw = &Ps[w][0];

  // Q fragments in registers for the whole loop (B-operand layout: col=li, k=q*8+j)
  bf16x8 qf[2][2];
#pragma unroll
  for (int bt = 0; bt < 2; ++bt)
#pragma unroll
    for (int kk = 0; kk < 2; ++kk)
      qf[bt][kk] = *(const bf16x8*)(Qb + (size_t)(n0 + w * 32 + bt * 16 + li) * 64 + kk * 32 + q * 8);

  f32x4 acc[4][2];   // O^T tiles: hdt(4) x bt(2)
#pragma unroll
  for (int i = 0; i < 4; ++i)
#pragma unroll
    for (int j = 0; j < 2; ++j) acc[i][j] = (f32x4){0.f, 0.f, 0.f, 0.f};
  float lsum[2] = {0.f, 0.f};

  for (int m0 = 0; m0 < 2048; m0 += 128) {
    __syncthreads();
    // stage K tile: 128 rows x 64 hd  (128*64 = 8192 elems -> 4 passes of 256 thr x 8)
#pragma unroll
    for (int p = 0; p < 4; ++p) {
      int idx = p * 256 + t;
      int row = idx >> 3, sg = (idx & 7) * 8;
      *(bf16x8*)&Ks[row * 72 + sg] = *(const bf16x8*)(Kb + (size_t)(m0 + row) * 64 + sg);
    }
    // stage V tile: 64 hd rows x 128 m
#pragma unroll
    for (int p = 0; p < 4; ++p) {
      int idx = p * 256 + t;
      int row = idx >> 4, sg = (idx & 15) * 8;
      *(bf16x8*)&Vs[row * 136 + sg] = *(const bf16x8*)(Vb + (size_t)row * 32768 + m0 + sg);
    }
    __syncthreads();

    // S^T = K * Q^T  (128 m-rows x 32 q-cols per wave)
    f32x4 sacc[8][2];
#pragma unroll
    for (int mt = 0; mt < 8; ++mt)
#pragma unroll
      for (int bt = 0; bt < 2; ++bt) sacc[mt][bt] = (f32x4){0.f, 0.f, 0.f, 0.f};
#pragma unroll
    for (int kk = 0; kk < 2; ++kk) {
#pragma unroll
      for (int mt = 0; mt < 8; ++mt) {
        bf16x8 af = *(const bf16x8*)&Ks[(mt * 16 + li) * 72 + kk * 32 + q * 8];
#pragma unroll
        for (int bt = 0; bt < 2; ++bt)
          sacc[mt][bt] = __builtin_amdgcn_mfma_f32_16x16x32_bf16(af, qf[bt][kk], sacc[mt][bt], 0, 0, 0);
      }
    }

    // fixed-max softmax numerator: P = 2^(S^T) (scale pre-folded into Q); store P^T to LDS
#pragma unroll
    for (int mt = 0; mt < 8; ++mt)
#pragma unroll
      for (int bt = 0; bt < 2; ++bt) {
        bf16x4 pk;
#pragma unroll
        for (int r = 0; r < 4; ++r) {
          float pv = exp2f(sacc[mt][bt][r]);
          lsum[bt] += pv;
          pk[r] = (bf16)pv;
        }
        *(bf16x4*)&Pw[(bt * 16 + li) * 136 + mt * 16 + q * 4] = pk;
      }
    // wave-private LDS region: DS ops complete in order per wave; just fence the compiler
    asm volatile("s_waitcnt lgkmcnt(0)" ::: "memory");

    // O^T += V * P^T
#pragma unroll
    for (int kk = 0; kk < 4; ++kk) {
      bf16x8 pf[2];
#pragma unroll
      for (int bt = 0; bt < 2; ++bt)
        pf[bt] = *(const bf16x8*)&Pw[(bt * 16 + li) * 136 + kk * 32 + q * 8];
#pragma unroll
      for (int hdt = 0; hdt < 4; ++hdt) {
        bf16x8 vf = *(const bf16x8*)&Vs[(hdt * 16 + li) * 136 + kk * 32 + q * 8];
#pragma unroll
        for (int bt = 0; bt < 2; ++bt)
          acc[hdt][bt] = __builtin_amdgcn_mfma_f32_16x16x32_bf16(vf, pf[bt], acc[hdt][bt], 0, 0, 0);
      }
    }
  }

  // deferred l reduction across the 4 q-quads (lane bits 4,5)
#pragma unroll
  for (int bt = 0; bt < 2; ++bt) {
    lsum[bt] += __shfl_xor(lsum[bt], 16);
    lsum[bt] += __shfl_xor(lsum[bt], 32);
  }
  float inv[2] = {1.0f / lsum[0], 1.0f / lsum[1]};

  // write x[b][n][h*64+hd]; O^T C-layout: hd = hdt*16 + q*4 + r (r-contig), qcol = bt*16+li
  bf16* xb = xo + (size_t)b * 2048 * 1024 + (size_t)h * 64;
#pragma unroll
  for (int hdt = 0; hdt < 4; ++hdt)
#pragma unroll
    for (int bt = 0; bt < 2; ++bt) {
      int n = n0 + w * 32 + bt * 16 + li;
      bf16x4 o;
#pragma unroll
      for (int r = 0; r < 4; ++r) o[r] = (bf16)(acc[hdt][bt][r] * inv[bt]);
      *(bf16x4*)(xb + (size_t)n * 1024 + hdt * 16 + q * 4) = o;
    }
}

// ---------------- K5: convert Wq/Wk/Wv f32 -> bf16 ----------------
__global__ __launch_bounds__(256) void k_cvtw(const float* __restrict__ Wq,
                                              const float* __restrict__ Wk,
                                              const float* __restrict__ Wv,
                                              bf16* __restrict__ oq,
                                              bf16* __restrict__ ok,
                                              bf16* __restrict__ ov) {
  const int which = blockIdx.y;
  const float* s = (which == 0) ? Wq : ((which == 1) ? Wk : Wv);
  bf16* d = (which == 0) ? oq : ((which == 1) ? ok : ov);
  int idx = (blockIdx.x * 256 + threadIdx.x) * 4;
  f32x4 a = *(const f32x4*)(s + idx);
  bf16x4 o;
#pragma unroll
  for (int e = 0; e < 4; ++e) o[e] = (bf16)a[e];
  *(bf16x4*)(d + idx) = o;
}

// ---------------- K6: permute Wm columns: Wmp[o][h*64+hd] = Wm[o][hd*16+h], f32->bf16 --
__global__ __launch_bounds__(256) void k_permw(const float* __restrict__ Wm,
                                               bf16* __restrict__ Wmp) {
  int idx = blockIdx.x * 256 + threadIdx.x;
  int o = idx >> 10, j = idx & 1023;
  int hd = j & 63, hh = j >> 6;
  Wmp[idx] = (bf16)Wm[((size_t)o << 10) + (size_t)(hd * 16 + hh)];
}

extern "C" void kernel_launch(void* const* d_in, const int* in_sizes, int n_in,
                              void* d_out, int out_size, void* d_ws, size_t ws_size,
                              hipStream_t stream) {
  const float* query = (const float*)d_in[0];
  const float* key   = (const float*)d_in[1];
  const float* value = (const float*)d_in[2];
  const float* enc   = (const float*)d_in[3];
  const float* Wq = (const float*)d_in[4];  const float* bq = (const float*)d_in[5];
  const float* Wk = (const float*)d_in[6];  const float* bk = (const float*)d_in[7];
  const float* Wv = (const float*)d_in[8];  const float* bv = (const float*)d_in[9];
  const float* Wm = (const float*)d_in[10]; const float* bm = (const float*)d_in[11];

  // Workspace: 4 ping-pong 16 MB buffers + 4 bf16 weights = 72 MB peak.
  char* ws = (char*)d_ws;
  const size_t SZ = (size_t)4 * 2048 * 1024 * 2;  // 16 MB per [b][*][*] bf16 tensor
  const size_t WZ = (size_t)1024 * 1024 * 2;      // 2 MB per bf16 weight
  bf16* bufA = (bf16*)(ws + 0 * SZ);
  bf16* bufB = (bf16*)(ws + 1 * SZ);
  bf16* bufC = (bf16*)(ws + 2 * SZ);
  bf16* bufD = (bf16*)(ws + 3 * SZ);
  bf16* Wqb  = (bf16*)(ws + 4 * SZ + 0 * WZ);
  bf16* Wkb  = (bf16*)(ws + 4 * SZ + 1 * WZ);
  bf16* Wvb  = (bf16*)(ws + 4 * SZ + 2 * WZ);
  bf16* Wmp  = (bf16*)(ws + 4 * SZ + 3 * WZ);

  dim3 blk(256);
  k_cvtw<<<dim3(1024, 3), blk, 0, stream>>>(Wq, Wk, Wv, Wqb, Wkb, Wvb);
  k_permw<<<dim3(4096), blk, 0, stream>>>(Wm, Wmp);
  // A = q^T ; B = qp
  k_transpose<<<dim3(32, 16, 4), blk, 0, stream>>>(query, bufA);
  k_gemm<bf16><<<dim3(16, 8, 4), blk, 0, stream>>>(Wqb, bufA, bq, bufB, 1024, 1024, 2048);
  // A = k^T ; C = kp
  k_transpose<<<dim3(32, 16, 4), blk, 0, stream>>>(key, bufA);
  k_gemm<bf16><<<dim3(16, 8, 4), blk, 0, stream>>>(Wkb, bufA, bk, bufC, 1024, 1024, 2048);
  // A = v^T ; D = vp
  k_transpose<<<dim3(32, 16, 4), blk, 0, stream>>>(value, bufA);
  k_gemm<bf16><<<dim3(16, 8, 4), blk, 0, stream>>>(Wvb, bufA, bv, bufD, 1024, 1024, 2048);
  // rope: B(qp) -> A(qa, pre-scaled); C(kp) -> B(ka)
  k_rope<<<dim3(32, 16, 4), blk, 0, stream>>>(bufB, enc, bufA, 0.125f * LOG2E);
  k_rope<<<dim3(32, 16, 4), blk, 0, stream>>>(bufC, enc, bufB, 1.0f);
  // attn: (A,B,D) -> C
  k_attn<<<dim3(16, 16, 4), blk, 0, stream>>>(bufA, bufB, bufD, bufC);
  // out GEMM: C -> d_out (f32)
  k_gemm<float><<<dim3(16, 8, 4), blk, 0, stream>>>(Wmp, bufC, bm, (float*)d_out, 1024, 1024, 2048);
}

// Round 6
// 408.537 us; speedup vs baseline: 1.3884x; 1.1765x over previous
//
#include <hip/hip_runtime.h>
#include <hip/hip_bf16.h>

typedef __bf16 bf16;
typedef __bf16 bf16x8 __attribute__((ext_vector_type(8)));
typedef __bf16 bf16x4 __attribute__((ext_vector_type(4)));
typedef float f32x4 __attribute__((ext_vector_type(4)));

#define LOG2E 1.44269504088896340736f

typedef __attribute__((address_space(1))) const unsigned int guint;
typedef __attribute__((address_space(3))) unsigned int luint;

__device__ __forceinline__ void gload_lds16(const bf16* g, bf16* l) {
  // async global->LDS, 16B per lane; LDS dest = wave-uniform base + lane*16
  __builtin_amdgcn_global_load_lds((guint*)g, (luint*)l, 16, 0, 0);
}

// ---------------- K1: transpose x[b][i][n] (f32) -> xt[b][n][i] (bf16), 64x64 tiles ----
__global__ __launch_bounds__(256) void k_transpose(const float* __restrict__ src,
                                                   bf16* __restrict__ dst) {
  __shared__ bf16 T[64][72];
  const int t = threadIdx.x;
  const int n0 = blockIdx.x * 64;
  const int i0 = blockIdx.y * 64;
  const int b = blockIdx.z;
  const size_t srcb = (size_t)b * 1024 * 2048;
#pragma unroll
  for (int p = 0; p < 2; ++p) {
    int idx = p * 256 + t;
    int row = idx >> 3;   // i-local
    int seg = idx & 7;    // 8 n elems
    const float* sp = src + srcb + (size_t)(i0 + row) * 2048 + n0 + seg * 8;
    f32x4 a = *(const f32x4*)sp;
    f32x4 c = *(const f32x4*)(sp + 4);
    bf16x8 o;
#pragma unroll
    for (int e = 0; e < 4; ++e) { o[e] = (bf16)a[e]; o[4 + e] = (bf16)c[e]; }
    *(bf16x8*)&T[row][seg * 8] = o;
  }
  __syncthreads();
  const int j = t >> 2;       // n-local
  const int iseg = t & 3;     // 16 i elems
  bf16x8 o0, o1;
#pragma unroll
  for (int e = 0; e < 8; ++e) o0[e] = T[iseg * 16 + e][j];
#pragma unroll
  for (int e = 0; e < 8; ++e) o1[e] = T[iseg * 16 + 8 + e][j];
  bf16* dp = dst + (size_t)b * 2048 * 1024 + (size_t)(n0 + j) * 1024 + i0 + iseg * 16;
  *(bf16x8*)dp = o0;
  *(bf16x8*)(dp + 8) = o1;
}

// ---------------- K2: GEMM  C[b][o][n] = W(o,k) * Bt[b][n][k] + bias[o] ----------------
// m97-style: global_load_lds width-16 staging into unpadded row-major [128][32] tiles.
template <typename OT>
__global__ __launch_bounds__(256) void k_gemm(const bf16* __restrict__ A,
                                              const bf16* __restrict__ Bt,
                                              const float* __restrict__ bias,
                                              OT* __restrict__ C,
                                              int M, int K, int Nn) {
  __shared__ bf16 As[128 * 32];
  __shared__ bf16 Bs[128 * 32];
  const int t = threadIdx.x;
  const int w = t >> 6, l = t & 63, q = l >> 4, li = l & 15;
  const int o0 = blockIdx.y * 128, n0 = blockIdx.x * 128;
  const int b = blockIdx.z;
  const bf16* Ab = A + (size_t)o0 * K;
  const bf16* Bb = Bt + (size_t)b * Nn * K + (size_t)n0 * K;
  const int wr = (w >> 1) * 64, wc = (w & 1) * 64;
  f32x4 acc[4][4];
#pragma unroll
  for (int i = 0; i < 4; ++i)
#pragma unroll
    for (int j = 0; j < 4; ++j) acc[i][j] = (f32x4){0.f, 0.f, 0.f, 0.f};

  // staging geometry: idx in [0,512): row = idx>>2 (128 rows), seg = idx&3 (4 x 8 elems)
  const int sidx0 = w * 64 + l;
  const int srow0 = sidx0 >> 2, sseg0 = (sidx0 & 3) * 8;
  const int sidx1 = 256 + sidx0;
  const int srow1 = sidx1 >> 2, sseg1 = (sidx1 & 3) * 8;
  bf16* ldsA0 = As + (size_t)(w * 64) * 8;        // wave-uniform bases
  bf16* ldsA1 = As + (size_t)(256 + w * 64) * 8;
  bf16* ldsB0 = Bs + (size_t)(w * 64) * 8;
  bf16* ldsB1 = Bs + (size_t)(256 + w * 64) * 8;

  for (int k0 = 0; k0 < K; k0 += 32) {
    __syncthreads();
    gload_lds16(Ab + (size_t)srow0 * K + k0 + sseg0, ldsA0);
    gload_lds16(Ab + (size_t)srow1 * K + k0 + sseg1, ldsA1);
    gload_lds16(Bb + (size_t)srow0 * K + k0 + sseg0, ldsB0);
    gload_lds16(Bb + (size_t)srow1 * K + k0 + sseg1, ldsB1);
    __syncthreads();
    bf16x8 af[4], bfr[4];
#pragma unroll
    for (int mt = 0; mt < 4; ++mt) af[mt] = *(const bf16x8*)&As[(wr + mt * 16 + li) * 32 + q * 8];
#pragma unroll
    for (int c = 0; c < 4; ++c) bfr[c] = *(const bf16x8*)&Bs[(wc + c * 16 + li) * 32 + q * 8];
#pragma unroll
    for (int mt = 0; mt < 4; ++mt)
#pragma unroll
      for (int c = 0; c < 4; ++c)
        acc[mt][c] = __builtin_amdgcn_mfma_f32_16x16x32_bf16(af[mt], bfr[c], acc[mt][c], 0, 0, 0);
  }

  OT* Cb = C + (size_t)b * M * Nn;
#pragma unroll
  for (int mt = 0; mt < 4; ++mt) {
#pragma unroll
    for (int r = 0; r < 4; ++r) {
      int o = o0 + wr + mt * 16 + q * 4 + r;
      float bv = bias[o];
#pragma unroll
      for (int c = 0; c < 4; ++c) {
        int n = n0 + wc + c * 16 + li;
        Cb[(size_t)o * Nn + n] = (OT)(acc[mt][c][r] + bv);
      }
    }
  }
}

// ---------------- K3: RoPE + per-head transpose: p[b][hd*16+h][n] -> a[b][h][n][hd] ----
// oscale folds the attention scale (and log2e) into Q so the attn kernel's softmax is
// a bare v_exp_f32.
__global__ __launch_bounds__(256) void k_rope(const bf16* __restrict__ src,
                                              const float* __restrict__ enc,
                                              bf16* __restrict__ dst,
                                              float oscale) {
  __shared__ bf16 T[64][72];
  const int t = threadIdx.x;
  const int n0 = blockIdx.x * 64;
  const int h = blockIdx.y;
  const int b = blockIdx.z;
#pragma unroll
  for (int p = 0; p < 2; ++p) {
    int idx = p * 256 + t;
    int hd = idx >> 3;   // hd-local (row d = hd*16+h)
    int seg = idx & 7;
    *(bf16x8*)&T[hd][seg * 8] =
        *(const bf16x8*)(src + (size_t)(b * 1024 + hd * 16 + h) * 2048 + n0 + seg * 8);
  }
  __syncthreads();
  const int j = t >> 2;          // n-local
  const int hd0 = (t & 3) * 16;  // 16 hd elems
  const int n = n0 + j;
  const float* e0 = enc + (size_t)n * 64 + hd0;
  const float* e1 = enc + (size_t)2048 * 64 + (size_t)n * 64 + hd0;
  bf16x8 o0, o1;
#pragma unroll
  for (int i = 0; i < 8; ++i) {
    int e = 2 * i;
    float t0 = (float)T[hd0 + e][j];
    float t1 = (float)T[hd0 + e + 1][j];
    float f00 = e0[e], f01 = e0[e + 1];
    float f10 = e1[e], f11 = e1[e + 1];
    float r0 = (t0 * f00 - t1 * f10) * oscale;
    float r1 = (t1 * f01 + t0 * f11) * oscale;
    if (i < 4) { o0[e & 7] = (bf16)r0; o0[(e & 7) + 1] = (bf16)r1; }
    else       { o1[e & 7] = (bf16)r0; o1[(e & 7) + 1] = (bf16)r1; }
  }
  bf16* dp = dst + ((size_t)(b * 16 + h) * 2048 + n) * 64 + hd0;
  *(bf16x8*)dp = o0;
  *(bf16x8*)(dp + 8) = o1;
}

// ---------------- K4: flash attention v3 ----------------
// S^T formulation, fixed-max softmax, K-tile 64 (LDS 36864 -> 4 blocks/CU),
// reg-prefetch staging pipeline, lsum via ones-MFMA on the idle matrix pipe.
// qa/ka: [b][h][n][hd] (hd contig; qa pre-scaled by 0.125*log2e). vp: [b][hd*16+h][n].
// out x: [b][n][h*64+hd].
__global__ __launch_bounds__(256, 4) void k_attn(const bf16* __restrict__ qa,
                                                 const bf16* __restrict__ ka,
                                                 const bf16* __restrict__ vp,
                                                 bf16* __restrict__ xo) {
  __shared__ bf16 Ks[64 * 72];     // [m][hd]
  __shared__ bf16 Vs[64 * 72];     // [hd][m]
  __shared__ bf16 Ps[4][32 * 72];  // per-wave P^T as [qcol][m]
  const int t = threadIdx.x;
  const int w = t >> 6, l = t & 63, q = l >> 4, li = l & 15;
  const int n0 = blockIdx.x * 128, h = blockIdx.y, b = blockIdx.z;
  const bf16* Qb = qa + (size_t)(b * 16 + h) * 2048 * 64;
  const bf16* Kb = ka + (size_t)(b * 16 + h) * 2048 * 64;
  const bf16* Vb = vp + (size_t)b * 1024 * 2048 + (size_t)h * 2048;  // + hd*16*2048
  bf16* Pw = &Ps[w][0];

  // staging geometry (64x64 tiles, 2 passes of 256 thr x 8 elems)
  const int r0 = t >> 3, s0 = (t & 7) * 8;            // pass 0: idx = t
  const int r1 = (256 + t) >> 3, s1 = (t & 7) * 8;    // pass 1

  // Q fragments in registers for the whole loop (B-operand layout: col=li, k=q*8+j)
  bf16x8 qf[2][2];
#pragma unroll
  for (int bt = 0; bt < 2; ++bt)
#pragma unroll
    for (int kk = 0; kk < 2; ++kk)
      qf[bt][kk] = *(const bf16x8*)(Qb + (size_t)(n0 + w * 32 + bt * 16 + li) * 64 + kk * 32 + q * 8);

  bf16x8 onef;
#pragma unroll
  for (int e = 0; e < 8; ++e) onef[e] = (bf16)1.0f;

  f32x4 acc[4][2];   // O^T tiles: hdt(4) x bt(2)
#pragma unroll
  for (int i = 0; i < 4; ++i)
#pragma unroll
    for (int j = 0; j < 2; ++j) acc[i][j] = (f32x4){0.f, 0.f, 0.f, 0.f};
  f32x4 accl[2] = {(f32x4){0.f, 0.f, 0.f, 0.f}, (f32x4){0.f, 0.f, 0.f, 0.f}};

  // prefetch registers
  bf16x8 kr0, kr1, vr0, vr1;
  kr0 = *(const bf16x8*)(Kb + (size_t)r0 * 64 + s0);
  kr1 = *(const bf16x8*)(Kb + (size_t)r1 * 64 + s1);
  vr0 = *(const bf16x8*)(Vb + (size_t)r0 * 32768 + s0);
  vr1 = *(const bf16x8*)(Vb + (size_t)r1 * 32768 + s1);
  *(bf16x8*)&Ks[r0 * 72 + s0] = kr0;
  *(bf16x8*)&Ks[r1 * 72 + s1] = kr1;
  *(bf16x8*)&Vs[r0 * 72 + s0] = vr0;
  *(bf16x8*)&Vs[r1 * 72 + s1] = vr1;
  __syncthreads();

  for (int m0 = 0; m0 < 2048; m0 += 64) {
    // issue next-tile loads (consumed after the barrier)
    const int mn = (m0 + 64 < 2048) ? m0 + 64 : m0;
    kr0 = *(const bf16x8*)(Kb + (size_t)(mn + r0) * 64 + s0);
    kr1 = *(const bf16x8*)(Kb + (size_t)(mn + r1) * 64 + s1);
    vr0 = *(const bf16x8*)(Vb + (size_t)r0 * 32768 + mn + s0);
    vr1 = *(const bf16x8*)(Vb + (size_t)r1 * 32768 + mn + s1);

    // S^T = K * Q^T  (64 m-rows x 32 q-cols per wave)
    f32x4 sacc[4][2];
#pragma unroll
    for (int mt = 0; mt < 4; ++mt)
#pragma unroll
      for (int bt = 0; bt < 2; ++bt) sacc[mt][bt] = (f32x4){0.f, 0.f, 0.f, 0.f};
#pragma unroll
    for (int kk = 0; kk < 2; ++kk) {
#pragma unroll
      for (int mt = 0; mt < 4; ++mt) {
        bf16x8 af = *(const bf16x8*)&Ks[(mt * 16 + li) * 72 + kk * 32 + q * 8];
#pragma unroll
        for (int bt = 0; bt < 2; ++bt)
          sacc[mt][bt] = __builtin_amdgcn_mfma_f32_16x16x32_bf16(af, qf[bt][kk], sacc[mt][bt], 0, 0, 0);
      }
    }

    // P = 2^(S^T) (scale pre-folded into Q); store P^T to per-wave LDS
#pragma unroll
    for (int mt = 0; mt < 4; ++mt)
#pragma unroll
      for (int bt = 0; bt < 2; ++bt) {
        bf16x4 pk;
#pragma unroll
        for (int r = 0; r < 4; ++r) pk[r] = (bf16)__builtin_amdgcn_exp2f(sacc[mt][bt][r]);
        *(bf16x4*)&Pw[(bt * 16 + li) * 72 + mt * 16 + q * 4] = pk;
      }
    // wave-private LDS region: DS ops complete in order per wave; fence before re-read
    asm volatile("s_waitcnt lgkmcnt(0)" ::: "memory");

    // O^T += V * P^T ; l += ones * P^T (row-sum on the matrix pipe)
#pragma unroll
    for (int kk = 0; kk < 2; ++kk) {
      bf16x8 pf[2];
#pragma unroll
      for (int bt = 0; bt < 2; ++bt) {
        pf[bt] = *(const bf16x8*)&Pw[(bt * 16 + li) * 72 + kk * 32 + q * 8];
        accl[bt] = __builtin_amdgcn_mfma_f32_16x16x32_bf16(onef, pf[bt], accl[bt], 0, 0, 0);
      }
#pragma unroll
      for (int hdt = 0; hdt < 4; ++hdt) {
        bf16x8 vf = *(const bf16x8*)&Vs[(hdt * 16 + li) * 72 + kk * 32 + q * 8];
#pragma unroll
        for (int bt = 0; bt < 2; ++bt)
          acc[hdt][bt] = __builtin_amdgcn_mfma_f32_16x16x32_bf16(vf, pf[bt], acc[hdt][bt], 0, 0, 0);
      }
    }

    __syncthreads();
    *(bf16x8*)&Ks[r0 * 72 + s0] = kr0;
    *(bf16x8*)&Ks[r1 * 72 + s1] = kr1;
    *(bf16x8*)&Vs[r0 * 72 + s0] = vr0;
    *(bf16x8*)&Vs[r1 * 72 + s1] = vr1;
    __syncthreads();
  }

  // l lands in C-layout col = li = q-col, all rows identical -> no shuffles needed
  float inv[2] = {1.0f / accl[0][0], 1.0f / accl[1][0]};

  // write x[b][n][h*64+hd]; O^T C-layout: hd = hdt*16 + q*4 + r (r-contig), qcol = bt*16+li
  bf16* xb = xo + (size_t)b * 2048 * 1024 + (size_t)h * 64;
#pragma unroll
  for (int hdt = 0; hdt < 4; ++hdt)
#pragma unroll
    for (int bt = 0; bt < 2; ++bt) {
      int n = n0 + w * 32 + bt * 16 + li;
      bf16x4 o;
#pragma unroll
      for (int r = 0; r < 4; ++r) o[r] = (bf16)(acc[hdt][bt][r] * inv[bt]);
      *(bf16x4*)(xb + (size_t)n * 1024 + hdt * 16 + q * 4) = o;
    }
}

// ---------------- K5: weight prep. y=0..2: cvt Wq/Wk/Wv f32->bf16. y=3: permute Wm. ----
__global__ __launch_bounds__(256) void k_prepw(const float* __restrict__ Wq,
                                               const float* __restrict__ Wk,
                                               const float* __restrict__ Wv,
                                               const float* __restrict__ Wm,
                                               bf16* __restrict__ oq,
                                               bf16* __restrict__ ok,
                                               bf16* __restrict__ ov,
                                               bf16* __restrict__ om) {
  const int which = blockIdx.y;
  if (which < 3) {
    const float* s = (which == 0) ? Wq : ((which == 1) ? Wk : Wv);
    bf16* d = (which == 0) ? oq : ((which == 1) ? ok : ov);
    int idx = (blockIdx.x * 256 + threadIdx.x) * 4;
    f32x4 a = *(const f32x4*)(s + idx);
    bf16x4 o;
#pragma unroll
    for (int e = 0; e < 4; ++e) o[e] = (bf16)a[e];
    *(bf16x4*)(d + idx) = o;
  } else {
    // Wmp[o][h*64+hd] = Wm[o][hd*16+h]
#pragma unroll
    for (int p = 0; p < 4; ++p) {
      int idx = (blockIdx.x * 4 + p) * 256 + threadIdx.x;
      int o = idx >> 10, j = idx & 1023;
      int hd = j & 63, hh = j >> 6;
      om[idx] = (bf16)Wm[((size_t)o << 10) + (size_t)(hd * 16 + hh)];
    }
  }
}

extern "C" void kernel_launch(void* const* d_in, const int* in_sizes, int n_in,
                              void* d_out, int out_size, void* d_ws, size_t ws_size,
                              hipStream_t stream) {
  const float* query = (const float*)d_in[0];
  const float* key   = (const float*)d_in[1];
  const float* value = (const float*)d_in[2];
  const float* enc   = (const float*)d_in[3];
  const float* Wq = (const float*)d_in[4];  const float* bq = (const float*)d_in[5];
  const float* Wk = (const float*)d_in[6];  const float* bk = (const float*)d_in[7];
  const float* Wv = (const float*)d_in[8];  const float* bv = (const float*)d_in[9];
  const float* Wm = (const float*)d_in[10]; const float* bm = (const float*)d_in[11];

  // Workspace: 4 ping-pong 16 MB buffers + 4 bf16 weights = 72 MB peak.
  char* ws = (char*)d_ws;
  const size_t SZ = (size_t)4 * 2048 * 1024 * 2;  // 16 MB per [b][*][*] bf16 tensor
  const size_t WZ = (size_t)1024 * 1024 * 2;      // 2 MB per bf16 weight
  bf16* bufA = (bf16*)(ws + 0 * SZ);
  bf16* bufB = (bf16*)(ws + 1 * SZ);
  bf16* bufC = (bf16*)(ws + 2 * SZ);
  bf16* bufD = (bf16*)(ws + 3 * SZ);
  bf16* Wqb  = (bf16*)(ws + 4 * SZ + 0 * WZ);
  bf16* Wkb  = (bf16*)(ws + 4 * SZ + 1 * WZ);
  bf16* Wvb  = (bf16*)(ws + 4 * SZ + 2 * WZ);
  bf16* Wmp  = (bf16*)(ws + 4 * SZ + 3 * WZ);

  dim3 blk(256);
  k_prepw<<<dim3(1024, 4), blk, 0, stream>>>(Wq, Wk, Wv, Wm, Wqb, Wkb, Wvb, Wmp);
  // A = q^T ; B = qp
  k_transpose<<<dim3(32, 16, 4), blk, 0, stream>>>(query, bufA);
  k_gemm<bf16><<<dim3(16, 8, 4), blk, 0, stream>>>(Wqb, bufA, bq, bufB, 1024, 1024, 2048);
  // A = k^T ; C = kp
  k_transpose<<<dim3(32, 16, 4), blk, 0, stream>>>(key, bufA);
  k_gemm<bf16><<<dim3(16, 8, 4), blk, 0, stream>>>(Wkb, bufA, bk, bufC, 1024, 1024, 2048);
  // A = v^T ; D = vp
  k_transpose<<<dim3(32, 16, 4), blk, 0, stream>>>(value, bufA);
  k_gemm<bf16><<<dim3(16, 8, 4), blk, 0, stream>>>(Wvb, bufA, bv, bufD, 1024, 1024, 2048);
  // rope: B(qp) -> A(qa, pre-scaled); C(kp) -> B(ka)
  k_rope<<<dim3(32, 16, 4), blk, 0, stream>>>(bufB, enc, bufA, 0.125f * LOG2E);
  k_rope<<<dim3(32, 16, 4), blk, 0, stream>>>(bufC, enc, bufB, 1.0f);
  // attn: (A,B,D) -> C
  k_attn<<<dim3(16, 16, 4), blk, 0, stream>>>(bufA, bufB, bufD, bufC);
  // out GEMM: C -> d_out (f32)
  k_gemm<float><<<dim3(16, 8, 4), blk, 0, stream>>>(Wmp, bufC, bm, (float*)d_out, 1024, 1024, 2048);
}

// Round 7
// 377.144 us; speedup vs baseline: 1.5040x; 1.0832x over previous
//
#include <hip/hip_runtime.h>
#include <hip/hip_bf16.h>

typedef __bf16 bf16;
typedef __bf16 bf16x8 __attribute__((ext_vector_type(8)));
typedef __bf16 bf16x4 __attribute__((ext_vector_type(4)));
typedef float f32x4 __attribute__((ext_vector_type(4)));

#define LOG2E 1.44269504088896340736f

typedef __attribute__((address_space(1))) const unsigned int guint;
typedef __attribute__((address_space(3))) unsigned int luint;

__device__ __forceinline__ void gload_lds16(const bf16* g, bf16* l) {
  // async global->LDS, 16B per lane; LDS dest = wave-uniform base + lane*16
  __builtin_amdgcn_global_load_lds((guint*)g, (luint*)l, 16, 0, 0);
}

// ------- K1: fused transpose x[b][i][n] (f32) -> xt[b][n][i] (bf16) for q,k,v ---------
__global__ __launch_bounds__(256) void k_transpose3(const float* __restrict__ q,
                                                    const float* __restrict__ k,
                                                    const float* __restrict__ v,
                                                    bf16* __restrict__ tq,
                                                    bf16* __restrict__ tk,
                                                    bf16* __restrict__ tv) {
  __shared__ bf16 T[64][72];
  const int t = threadIdx.x;
  const int n0 = blockIdx.x * 64;
  const int i0 = blockIdx.y * 64;
  const int z = blockIdx.z;
  const int b = z & 3, which = z >> 2;
  const float* src = (which == 0) ? q : ((which == 1) ? k : v);
  bf16* dst = (which == 0) ? tq : ((which == 1) ? tk : tv);
  const size_t srcb = (size_t)b * 1024 * 2048;
#pragma unroll
  for (int p = 0; p < 2; ++p) {
    int idx = p * 256 + t;
    int row = idx >> 3;   // i-local
    int seg = idx & 7;    // 8 n elems
    const float* sp = src + srcb + (size_t)(i0 + row) * 2048 + n0 + seg * 8;
    f32x4 a = *(const f32x4*)sp;
    f32x4 c = *(const f32x4*)(sp + 4);
    bf16x8 o;
#pragma unroll
    for (int e = 0; e < 4; ++e) { o[e] = (bf16)a[e]; o[4 + e] = (bf16)c[e]; }
    *(bf16x8*)&T[row][seg * 8] = o;
  }
  __syncthreads();
  const int j = t >> 2;       // n-local
  const int iseg = t & 3;     // 16 i elems
  bf16x8 o0, o1;
#pragma unroll
  for (int e = 0; e < 8; ++e) o0[e] = T[iseg * 16 + e][j];
#pragma unroll
  for (int e = 0; e < 8; ++e) o1[e] = T[iseg * 16 + 8 + e][j];
  bf16* dp = dst + (size_t)b * 2048 * 1024 + (size_t)(n0 + j) * 1024 + i0 + iseg * 16;
  *(bf16x8*)dp = o0;
  *(bf16x8*)(dp + 8) = o1;
}

// ------- K2a: fused QKV GEMM  C[b][o][n] = W(o,k)*Bt[b][n][k] + bias[o], z = which*4+b -
__global__ __launch_bounds__(256) void k_gemm3(const bf16* __restrict__ Wqb,
                                               const bf16* __restrict__ Wkb,
                                               const bf16* __restrict__ Wvb,
                                               const float* __restrict__ bq,
                                               const float* __restrict__ bk,
                                               const float* __restrict__ bv,
                                               const bf16* __restrict__ tq,
                                               const bf16* __restrict__ tk,
                                               const bf16* __restrict__ tv,
                                               bf16* __restrict__ qp,
                                               bf16* __restrict__ kp,
                                               bf16* __restrict__ vp) {
  const int K = 1024, Nn = 2048;
  const int z = blockIdx.z;
  const int b = z & 3, which = z >> 2;
  const bf16* A = (which == 0) ? Wqb : ((which == 1) ? Wkb : Wvb);
  const bf16* Bt = (which == 0) ? tq : ((which == 1) ? tk : tv);
  const float* bias = (which == 0) ? bq : ((which == 1) ? bk : bv);
  bf16* C = (which == 0) ? qp : ((which == 1) ? kp : vp);

  __shared__ bf16 As[128 * 32];
  __shared__ bf16 Bs[128 * 32];
  const int t = threadIdx.x;
  const int w = t >> 6, l = t & 63, q = l >> 4, li = l & 15;
  const int o0 = blockIdx.y * 128, n0 = blockIdx.x * 128;
  const bf16* Ab = A + (size_t)o0 * K;
  const bf16* Bb = Bt + (size_t)b * Nn * K + (size_t)n0 * K;
  const int wr = (w >> 1) * 64, wc = (w & 1) * 64;
  f32x4 acc[4][4];
#pragma unroll
  for (int i = 0; i < 4; ++i)
#pragma unroll
    for (int j = 0; j < 4; ++j) acc[i][j] = (f32x4){0.f, 0.f, 0.f, 0.f};

  const int sidx0 = w * 64 + l;
  const int srow0 = sidx0 >> 2, sseg0 = (sidx0 & 3) * 8;
  const int sidx1 = 256 + sidx0;
  const int srow1 = sidx1 >> 2, sseg1 = (sidx1 & 3) * 8;
  bf16* ldsA0 = As + (size_t)(w * 64) * 8;
  bf16* ldsA1 = As + (size_t)(256 + w * 64) * 8;
  bf16* ldsB0 = Bs + (size_t)(w * 64) * 8;
  bf16* ldsB1 = Bs + (size_t)(256 + w * 64) * 8;

  for (int k0 = 0; k0 < K; k0 += 32) {
    __syncthreads();
    gload_lds16(Ab + (size_t)srow0 * K + k0 + sseg0, ldsA0);
    gload_lds16(Ab + (size_t)srow1 * K + k0 + sseg1, ldsA1);
    gload_lds16(Bb + (size_t)srow0 * K + k0 + sseg0, ldsB0);
    gload_lds16(Bb + (size_t)srow1 * K + k0 + sseg1, ldsB1);
    __syncthreads();
    bf16x8 af[4], bfr[4];
#pragma unroll
    for (int mt = 0; mt < 4; ++mt) af[mt] = *(const bf16x8*)&As[(wr + mt * 16 + li) * 32 + q * 8];
#pragma unroll
    for (int c = 0; c < 4; ++c) bfr[c] = *(const bf16x8*)&Bs[(wc + c * 16 + li) * 32 + q * 8];
#pragma unroll
    for (int mt = 0; mt < 4; ++mt)
#pragma unroll
      for (int c = 0; c < 4; ++c)
        acc[mt][c] = __builtin_amdgcn_mfma_f32_16x16x32_bf16(af[mt], bfr[c], acc[mt][c], 0, 0, 0);
  }

  bf16* Cb = C + (size_t)b * K * Nn;
#pragma unroll
  for (int mt = 0; mt < 4; ++mt) {
#pragma unroll
    for (int r = 0; r < 4; ++r) {
      int o = o0 + wr + mt * 16 + q * 4 + r;
      float bvv = bias[o];
#pragma unroll
      for (int c = 0; c < 4; ++c) {
        int n = n0 + wc + c * 16 + li;
        Cb[(size_t)o * Nn + n] = (bf16)(acc[mt][c][r] + bvv);
      }
    }
  }
}

// ------- K2b: single GEMM (final projection), OT = float --------------------------------
template <typename OT>
__global__ __launch_bounds__(256) void k_gemm(const bf16* __restrict__ A,
                                              const bf16* __restrict__ Bt,
                                              const float* __restrict__ bias,
                                              OT* __restrict__ C,
                                              int M, int K, int Nn) {
  __shared__ bf16 As[128 * 32];
  __shared__ bf16 Bs[128 * 32];
  const int t = threadIdx.x;
  const int w = t >> 6, l = t & 63, q = l >> 4, li = l & 15;
  const int o0 = blockIdx.y * 128, n0 = blockIdx.x * 128;
  const int b = blockIdx.z;
  const bf16* Ab = A + (size_t)o0 * K;
  const bf16* Bb = Bt + (size_t)b * Nn * K + (size_t)n0 * K;
  const int wr = (w >> 1) * 64, wc = (w & 1) * 64;
  f32x4 acc[4][4];
#pragma unroll
  for (int i = 0; i < 4; ++i)
#pragma unroll
    for (int j = 0; j < 4; ++j) acc[i][j] = (f32x4){0.f, 0.f, 0.f, 0.f};

  const int sidx0 = w * 64 + l;
  const int srow0 = sidx0 >> 2, sseg0 = (sidx0 & 3) * 8;
  const int sidx1 = 256 + sidx0;
  const int srow1 = sidx1 >> 2, sseg1 = (sidx1 & 3) * 8;
  bf16* ldsA0 = As + (size_t)(w * 64) * 8;
  bf16* ldsA1 = As + (size_t)(256 + w * 64) * 8;
  bf16* ldsB0 = Bs + (size_t)(w * 64) * 8;
  bf16* ldsB1 = Bs + (size_t)(256 + w * 64) * 8;

  for (int k0 = 0; k0 < K; k0 += 32) {
    __syncthreads();
    gload_lds16(Ab + (size_t)srow0 * K + k0 + sseg0, ldsA0);
    gload_lds16(Ab + (size_t)srow1 * K + k0 + sseg1, ldsA1);
    gload_lds16(Bb + (size_t)srow0 * K + k0 + sseg0, ldsB0);
    gload_lds16(Bb + (size_t)srow1 * K + k0 + sseg1, ldsB1);
    __syncthreads();
    bf16x8 af[4], bfr[4];
#pragma unroll
    for (int mt = 0; mt < 4; ++mt) af[mt] = *(const bf16x8*)&As[(wr + mt * 16 + li) * 32 + q * 8];
#pragma unroll
    for (int c = 0; c < 4; ++c) bfr[c] = *(const bf16x8*)&Bs[(wc + c * 16 + li) * 32 + q * 8];
#pragma unroll
    for (int mt = 0; mt < 4; ++mt)
#pragma unroll
      for (int c = 0; c < 4; ++c)
        acc[mt][c] = __builtin_amdgcn_mfma_f32_16x16x32_bf16(af[mt], bfr[c], acc[mt][c], 0, 0, 0);
  }

  OT* Cb = C + (size_t)b * M * Nn;
#pragma unroll
  for (int mt = 0; mt < 4; ++mt) {
#pragma unroll
    for (int r = 0; r < 4; ++r) {
      int o = o0 + wr + mt * 16 + q * 4 + r;
      float bv = bias[o];
#pragma unroll
      for (int c = 0; c < 4; ++c) {
        int n = n0 + wc + c * 16 + li;
        Cb[(size_t)o * Nn + n] = (OT)(acc[mt][c][r] + bv);
      }
    }
  }
}

// ------- K3: fused RoPE q&k: p[b][hd*16+h][n] -> a[b][h][n][hd], z = which*4+b ---------
__global__ __launch_bounds__(256) void k_rope2(const bf16* __restrict__ qp,
                                               const bf16* __restrict__ kp,
                                               const float* __restrict__ enc,
                                               bf16* __restrict__ qa,
                                               bf16* __restrict__ ka) {
  __shared__ bf16 T[64][72];
  const int t = threadIdx.x;
  const int n0 = blockIdx.x * 64;
  const int h = blockIdx.y;
  const int z = blockIdx.z;
  const int b = z & 3, which = z >> 2;
  const bf16* src = which ? kp : qp;
  bf16* dst = which ? ka : qa;
  const float oscale = which ? 1.0f : 0.125f * LOG2E;
#pragma unroll
  for (int p = 0; p < 2; ++p) {
    int idx = p * 256 + t;
    int hd = idx >> 3;   // hd-local (row d = hd*16+h)
    int seg = idx & 7;
    *(bf16x8*)&T[hd][seg * 8] =
        *(const bf16x8*)(src + (size_t)(b * 1024 + hd * 16 + h) * 2048 + n0 + seg * 8);
  }
  __syncthreads();
  const int j = t >> 2;          // n-local
  const int hd0 = (t & 3) * 16;  // 16 hd elems
  const int n = n0 + j;
  const float* e0 = enc + (size_t)n * 64 + hd0;
  const float* e1 = enc + (size_t)2048 * 64 + (size_t)n * 64 + hd0;
  bf16x8 o0, o1;
#pragma unroll
  for (int i = 0; i < 8; ++i) {
    int e = 2 * i;
    float t0 = (float)T[hd0 + e][j];
    float t1 = (float)T[hd0 + e + 1][j];
    float f00 = e0[e], f01 = e0[e + 1];
    float f10 = e1[e], f11 = e1[e + 1];
    float r0 = (t0 * f00 - t1 * f10) * oscale;
    float r1 = (t1 * f01 + t0 * f11) * oscale;
    if (i < 4) { o0[e & 7] = (bf16)r0; o0[(e & 7) + 1] = (bf16)r1; }
    else       { o1[e & 7] = (bf16)r0; o1[(e & 7) + 1] = (bf16)r1; }
  }
  bf16* dp = dst + ((size_t)(b * 16 + h) * 2048 + n) * 64 + hd0;
  *(bf16x8*)dp = o0;
  *(bf16x8*)(dp + 8) = o1;
}

// ---------------- K4: flash attention v3 (unchanged from round 6) ----------------------
__global__ __launch_bounds__(256, 4) void k_attn(const bf16* __restrict__ qa,
                                                 const bf16* __restrict__ ka,
                                                 const bf16* __restrict__ vp,
                                                 bf16* __restrict__ xo) {
  __shared__ bf16 Ks[64 * 72];     // [m][hd]
  __shared__ bf16 Vs[64 * 72];     // [hd][m]
  __shared__ bf16 Ps[4][32 * 72];  // per-wave P^T as [qcol][m]
  const int t = threadIdx.x;
  const int w = t >> 6, l = t & 63, q = l >> 4, li = l & 15;
  const int n0 = blockIdx.x * 128, h = blockIdx.y, b = blockIdx.z;
  const bf16* Qb = qa + (size_t)(b * 16 + h) * 2048 * 64;
  const bf16* Kb = ka + (size_t)(b * 16 + h) * 2048 * 64;
  const bf16* Vb = vp + (size_t)b * 1024 * 2048 + (size_t)h * 2048;  // + hd*16*2048
  bf16* Pw = &Ps[w][0];

  const int r0 = t >> 3, s0 = (t & 7) * 8;
  const int r1 = (256 + t) >> 3, s1 = (t & 7) * 8;

  bf16x8 qf[2][2];
#pragma unroll
  for (int bt = 0; bt < 2; ++bt)
#pragma unroll
    for (int kk = 0; kk < 2; ++kk)
      qf[bt][kk] = *(const bf16x8*)(Qb + (size_t)(n0 + w * 32 + bt * 16 + li) * 64 + kk * 32 + q * 8);

  bf16x8 onef;
#pragma unroll
  for (int e = 0; e < 8; ++e) onef[e] = (bf16)1.0f;

  f32x4 acc[4][2];
#pragma unroll
  for (int i = 0; i < 4; ++i)
#pragma unroll
    for (int j = 0; j < 2; ++j) acc[i][j] = (f32x4){0.f, 0.f, 0.f, 0.f};
  f32x4 accl[2] = {(f32x4){0.f, 0.f, 0.f, 0.f}, (f32x4){0.f, 0.f, 0.f, 0.f}};

  bf16x8 kr0, kr1, vr0, vr1;
  kr0 = *(const bf16x8*)(Kb + (size_t)r0 * 64 + s0);
  kr1 = *(const bf16x8*)(Kb + (size_t)r1 * 64 + s1);
  vr0 = *(const bf16x8*)(Vb + (size_t)r0 * 32768 + s0);
  vr1 = *(const bf16x8*)(Vb + (size_t)r1 * 32768 + s1);
  *(bf16x8*)&Ks[r0 * 72 + s0] = kr0;
  *(bf16x8*)&Ks[r1 * 72 + s1] = kr1;
  *(bf16x8*)&Vs[r0 * 72 + s0] = vr0;
  *(bf16x8*)&Vs[r1 * 72 + s1] = vr1;
  __syncthreads();

  for (int m0 = 0; m0 < 2048; m0 += 64) {
    const int mn = (m0 + 64 < 2048) ? m0 + 64 : m0;
    kr0 = *(const bf16x8*)(Kb + (size_t)(mn + r0) * 64 + s0);
    kr1 = *(const bf16x8*)(Kb + (size_t)(mn + r1) * 64 + s1);
    vr0 = *(const bf16x8*)(Vb + (size_t)r0 * 32768 + mn + s0);
    vr1 = *(const bf16x8*)(Vb + (size_t)r1 * 32768 + mn + s1);

    f32x4 sacc[4][2];
#pragma unroll
    for (int mt = 0; mt < 4; ++mt)
#pragma unroll
      for (int bt = 0; bt < 2; ++bt) sacc[mt][bt] = (f32x4){0.f, 0.f, 0.f, 0.f};
#pragma unroll
    for (int kk = 0; kk < 2; ++kk) {
#pragma unroll
      for (int mt = 0; mt < 4; ++mt) {
        bf16x8 af = *(const bf16x8*)&Ks[(mt * 16 + li) * 72 + kk * 32 + q * 8];
#pragma unroll
        for (int bt = 0; bt < 2; ++bt)
          sacc[mt][bt] = __builtin_amdgcn_mfma_f32_16x16x32_bf16(af, qf[bt][kk], sacc[mt][bt], 0, 0, 0);
      }
    }

#pragma unroll
    for (int mt = 0; mt < 4; ++mt)
#pragma unroll
      for (int bt = 0; bt < 2; ++bt) {
        bf16x4 pk;
#pragma unroll
        for (int r = 0; r < 4; ++r) pk[r] = (bf16)__builtin_amdgcn_exp2f(sacc[mt][bt][r]);
        *(bf16x4*)&Pw[(bt * 16 + li) * 72 + mt * 16 + q * 4] = pk;
      }
    asm volatile("s_waitcnt lgkmcnt(0)" ::: "memory");

#pragma unroll
    for (int kk = 0; kk < 2; ++kk) {
      bf16x8 pf[2];
#pragma unroll
      for (int bt = 0; bt < 2; ++bt) {
        pf[bt] = *(const bf16x8*)&Pw[(bt * 16 + li) * 72 + kk * 32 + q * 8];
        accl[bt] = __builtin_amdgcn_mfma_f32_16x16x32_bf16(onef, pf[bt], accl[bt], 0, 0, 0);
      }
#pragma unroll
      for (int hdt = 0; hdt < 4; ++hdt) {
        bf16x8 vf = *(const bf16x8*)&Vs[(hdt * 16 + li) * 72 + kk * 32 + q * 8];
#pragma unroll
        for (int bt = 0; bt < 2; ++bt)
          acc[hdt][bt] = __builtin_amdgcn_mfma_f32_16x16x32_bf16(vf, pf[bt], acc[hdt][bt], 0, 0, 0);
      }
    }

    __syncthreads();
    *(bf16x8*)&Ks[r0 * 72 + s0] = kr0;
    *(bf16x8*)&Ks[r1 * 72 + s1] = kr1;
    *(bf16x8*)&Vs[r0 * 72 + s0] = vr0;
    *(bf16x8*)&Vs[r1 * 72 + s1] = vr1;
    __syncthreads();
  }

  float inv[2] = {1.0f / accl[0][0], 1.0f / accl[1][0]};

  bf16* xb = xo + (size_t)b * 2048 * 1024 + (size_t)h * 64;
#pragma unroll
  for (int hdt = 0; hdt < 4; ++hdt)
#pragma unroll
    for (int bt = 0; bt < 2; ++bt) {
      int n = n0 + w * 32 + bt * 16 + li;
      bf16x4 o;
#pragma unroll
      for (int r = 0; r < 4; ++r) o[r] = (bf16)(acc[hdt][bt][r] * inv[bt]);
      *(bf16x4*)(xb + (size_t)n * 1024 + hdt * 16 + q * 4) = o;
    }
}

// ---------------- K5: weight prep. y=0..2: cvt Wq/Wk/Wv f32->bf16. y=3: permute Wm. ----
__global__ __launch_bounds__(256) void k_prepw(const float* __restrict__ Wq,
                                               const float* __restrict__ Wk,
                                               const float* __restrict__ Wv,
                                               const float* __restrict__ Wm,
                                               bf16* __restrict__ oq,
                                               bf16* __restrict__ ok,
                                               bf16* __restrict__ ov,
                                               bf16* __restrict__ om) {
  const int which = blockIdx.y;
  if (which < 3) {
    const float* s = (which == 0) ? Wq : ((which == 1) ? Wk : Wv);
    bf16* d = (which == 0) ? oq : ((which == 1) ? ok : ov);
    int idx = (blockIdx.x * 256 + threadIdx.x) * 4;
    f32x4 a = *(const f32x4*)(s + idx);
    bf16x4 o;
#pragma unroll
    for (int e = 0; e < 4; ++e) o[e] = (bf16)a[e];
    *(bf16x4*)(d + idx) = o;
  } else {
    // Wmp[o][h*64+hd] = Wm[o][hd*16+h]
#pragma unroll
    for (int p = 0; p < 4; ++p) {
      int idx = (blockIdx.x * 4 + p) * 256 + threadIdx.x;
      int o = idx >> 10, j = idx & 1023;
      int hd = j & 63, hh = j >> 6;
      om[idx] = (bf16)Wm[((size_t)o << 10) + (size_t)(hd * 16 + hh)];
    }
  }
}

extern "C" void kernel_launch(void* const* d_in, const int* in_sizes, int n_in,
                              void* d_out, int out_size, void* d_ws, size_t ws_size,
                              hipStream_t stream) {
  const float* query = (const float*)d_in[0];
  const float* key   = (const float*)d_in[1];
  const float* value = (const float*)d_in[2];
  const float* enc   = (const float*)d_in[3];
  const float* Wq = (const float*)d_in[4];  const float* bq = (const float*)d_in[5];
  const float* Wk = (const float*)d_in[6];  const float* bk = (const float*)d_in[7];
  const float* Wv = (const float*)d_in[8];  const float* bv = (const float*)d_in[9];
  const float* Wm = (const float*)d_in[10]; const float* bm = (const float*)d_in[11];

  // Workspace: 4 x 16 MB bf16 buffers + 4 x 2 MB bf16 weights = 72 MB (validated budget).
  // d_out (33.5 MB f32) doubles as scratch for v^T and vp until the final GEMM
  // overwrites every element of it.
  char* ws = (char*)d_ws;
  const size_t SZ = (size_t)4 * 2048 * 1024 * 2;  // 16 MB per [b][*][*] bf16 tensor
  const size_t WZ = (size_t)1024 * 1024 * 2;      // 2 MB per bf16 weight
  bf16* bufA = (bf16*)(ws + 0 * SZ);
  bf16* bufB = (bf16*)(ws + 1 * SZ);
  bf16* bufC = (bf16*)(ws + 2 * SZ);
  bf16* bufD = (bf16*)(ws + 3 * SZ);
  bf16* Wqb  = (bf16*)(ws + 4 * SZ + 0 * WZ);
  bf16* Wkb  = (bf16*)(ws + 4 * SZ + 1 * WZ);
  bf16* Wvb  = (bf16*)(ws + 4 * SZ + 2 * WZ);
  bf16* Wmp  = (bf16*)(ws + 4 * SZ + 3 * WZ);
  bf16* vt   = (bf16*)d_out;                          // v^T scratch (16 MB)
  bf16* vpd  = (bf16*)d_out + (size_t)4 * 2048 * 1024; // vp scratch (16 MB)

  dim3 blk(256);
  // weights
  k_prepw<<<dim3(1024, 4), blk, 0, stream>>>(Wq, Wk, Wv, Wm, Wqb, Wkb, Wvb, Wmp);
  // transposes: q->A, k->B, v->vt (d_out scratch)
  k_transpose3<<<dim3(32, 16, 12), blk, 0, stream>>>(query, key, value, bufA, bufB, vt);
  // fused QKV GEMM (z=12, 1536 blocks = 6 blocks/CU): (Wq,A)->C, (Wk,B)->D, (Wv,vt)->vpd
  k_gemm3<<<dim3(16, 8, 12), blk, 0, stream>>>(Wqb, Wkb, Wvb, bq, bk, bv,
                                               bufA, bufB, vt, bufC, bufD, vpd);
  // fused rope (z=8): qp(C)->A (pre-scaled), kp(D)->B
  k_rope2<<<dim3(32, 16, 8), blk, 0, stream>>>(bufC, bufD, enc, bufA, bufB);
  // attn: (A,B,vpd) -> C
  k_attn<<<dim3(16, 16, 4), blk, 0, stream>>>(bufA, bufB, vpd, bufC);
  // out GEMM: C -> d_out (f32, overwrites scratch)
  k_gemm<float><<<dim3(16, 8, 4), blk, 0, stream>>>(Wmp, bufC, bm, (float*)d_out, 1024, 1024, 2048);
}